// Round 2
// baseline (242.629 us; speedup 1.0000x reference)
//
#include <hip/hip_runtime.h>
#include <hip/hip_bf16.h>
#include <cstddef>

// Problem constants (from reference setup_inputs)
#define BB 16
#define CC 192
#define HH 64
#define WW 64
#define LL 4096   // H*W
#define DTR 12    // dt_rank
#define KK 14     // dt_rank + 2*d_state, d_state = 1

__device__ __forceinline__ float silu_f(float v) {
  return v / (1.f + __expf(-v));
}

// ---------------------------------------------------------------------------
// K1: depthwise 5x5 conv (SAME, zero pad) + bias + SiLU
// one block per (b,c) plane; 68x72 halo tile in LDS; 4x4 px per thread,
// register-cached 8x12 input window via ds_read_b128 (24 per thread).
// ---------------------------------------------------------------------------
__global__ __launch_bounds__(256) void conv_silu_kernel(
    const float* __restrict__ x, const float* __restrict__ cw,
    const float* __restrict__ cb, float* __restrict__ xs) {
  const int bc = blockIdx.x;           // b*CC + c
  const int c = bc % CC;
  const int tid = threadIdx.x;
  __shared__ float sm[68 * 72];

  const float* xp = x + (size_t)bc * LL;
  // halo load: logical input (gy,gx) -> sm[(gy+2)*72 + gx+4], zero outside
  for (int i = tid; i < 68 * 72; i += 256) {
    int r = i / 72;
    int col = i - r * 72;
    int gy = r - 2, gx = col - 4;
    float v = 0.f;
    if ((unsigned)gy < 64u && (unsigned)gx < 64u) v = xp[gy * 64 + gx];
    sm[i] = v;
  }
  float w[25];
#pragma unroll
  for (int k = 0; k < 25; ++k) w[k] = cw[c * 25 + k];
  const float bias = cb[c];
  __syncthreads();

  const int tx = tid & 15, ty = tid >> 4;
  const int ox = tx * 4, oy0 = ty * 4;

  // register window: input rows oy0-2 .. oy0+5 (sm rows oy0..oy0+7),
  // sm cols ox..ox+11 (logical gx = ox-4 .. ox+7)
  float rb[8][12];
#pragma unroll
  for (int r = 0; r < 8; ++r) {
    const float* rp = &sm[(oy0 + r) * 72 + ox];
    *(float4*)&rb[r][0] = *(const float4*)(rp);
    *(float4*)&rb[r][4] = *(const float4*)(rp + 4);
    *(float4*)&rb[r][8] = *(const float4*)(rp + 8);
  }

  float* op = xs + (size_t)bc * LL;
#pragma unroll
  for (int ry = 0; ry < 4; ++ry) {
    float acc[4] = {bias, bias, bias, bias};
#pragma unroll
    for (int ky = 0; ky < 5; ++ky) {
#pragma unroll
      for (int kx = 0; kx < 5; ++kx) {
        float wv = w[ky * 5 + kx];
#pragma unroll
        for (int oi = 0; oi < 4; ++oi)
          acc[oi] += rb[ry + ky][2 + oi + kx] * wv;
      }
    }
    float4 o;
    o.x = silu_f(acc[0]);
    o.y = silu_f(acc[1]);
    o.z = silu_f(acc[2]);
    o.w = silu_f(acc[3]);
    *(float4*)(op + (oy0 + ry) * 64 + ox) = o;
  }
}

// ---------------------------------------------------------------------------
// K2: x_dbl[b][k][l] = sum_c x_proj_w[k][c] * xs[b][c][l]   (k = 0..13)
// rows 0..11 = dts, 12 = Bs, 13 = Cs. block = (128 l's, b); 4 waves x 48 ch.
// ---------------------------------------------------------------------------
__global__ __launch_bounds__(256) void proj_kernel(
    const float* __restrict__ xs, const float* __restrict__ xpw,
    float* __restrict__ xdbl) {
  const int b = blockIdx.y;
  const int l0 = blockIdx.x * 128;
  const int tid = threadIdx.x;
  const int lane = tid & 63;
  const int g = tid >> 6;  // wave id, 0..3

  __shared__ float part[4][KK][128];

  float acc[KK][2];
#pragma unroll
  for (int k = 0; k < KK; ++k) acc[k][0] = acc[k][1] = 0.f;

  const float* base = xs + ((size_t)b * CC + g * 48) * LL + l0 + lane * 2;
#pragma unroll 4
  for (int cc = 0; cc < 48; ++cc) {
    float2 v = *(const float2*)(base + (size_t)cc * LL);
    int c = g * 48 + cc;
#pragma unroll
    for (int k = 0; k < KK; ++k) {
      float wv = xpw[k * CC + c];
      acc[k][0] += wv * v.x;
      acc[k][1] += wv * v.y;
    }
  }
#pragma unroll
  for (int k = 0; k < KK; ++k)
    *(float2*)&part[g][k][lane * 2] = make_float2(acc[k][0], acc[k][1]);
  __syncthreads();

  // reduce 4 partials, write out (KK*128 = 1792 values, 7 iters)
  for (int idx = tid; idx < KK * 128; idx += 256) {
    int k = idx >> 7, ln = idx & 127;
    float v = part[0][k][ln] + part[1][k][ln] + part[2][k][ln] + part[3][k][ln];
    xdbl[((size_t)b * KK + k) * LL + l0 + ln] = v;
  }
}

// ---------------------------------------------------------------------------
// K3: fused dt-projection + softplus + selective scan + output.
// delta = softplus(dt_b[c] + dt_w[c,:]·dts[b,:,l])
// h_t = exp(delta_t*A_c)*h_{t-1} + delta_t*Bs_t*xs_t;  y = h*Cs + xs*Ds
// block = (b,c); 256 threads x 16 contiguous l's; affine block scan.
// ---------------------------------------------------------------------------
__global__ __launch_bounds__(256) void scan_kernel(
    const float* __restrict__ xs, const float* __restrict__ xdbl,
    const float* __restrict__ dtw, const float* __restrict__ dtb,
    const float* __restrict__ A_logs, const float* __restrict__ Ds,
    float* __restrict__ y) {
  const int bc = blockIdx.x;
  const int b = bc / CC;
  const int c = bc - b * CC;
  const int tid = threadIdx.x;
  const int lane = tid & 63;
  const int wid = tid >> 6;

  const float Ac = -__expf(A_logs[c]);  // d_state = 1
  const float Dc = Ds[c];
  float dw[DTR];
#pragma unroll
  for (int r = 0; r < DTR; ++r) dw[r] = dtw[c * DTR + r];
  const float db = dtb[c];

  const float* xp = xs + (size_t)bc * LL;
  const float* xb = xdbl + (size_t)b * KK * LL;
  float* yp = y + (size_t)bc * LL;

  const int base = tid * 16;

  float av[16], bv[16], xd[16];
  float aggA = 1.f, aggB = 0.f;

  // phase 1: compute delta inline, per-element terms, local composition
#pragma unroll
  for (int j = 0; j < 4; ++j) {
    float4 x4 = *(const float4*)(xp + base + j * 4);
    float4 B4 = *(const float4*)(xb + 12 * LL + base + j * 4);
    float4 dr[DTR];
#pragma unroll
    for (int r = 0; r < DTR; ++r)
      dr[r] = *(const float4*)(xb + r * LL + base + j * 4);
    float xx[4] = {x4.x, x4.y, x4.z, x4.w};
    float bb[4] = {B4.x, B4.y, B4.z, B4.w};
#pragma unroll
    for (int q = 0; q < 4; ++q) {
      int i = j * 4 + q;
      float z = db;
#pragma unroll
      for (int r = 0; r < DTR; ++r) z += dw[r] * ((&dr[r].x)[q]);
      float delta = (z > 15.f) ? z : __logf(1.f + __expf(z));
      float a = __expf(delta * Ac);
      float be = delta * bb[q] * xx[q];
      av[i] = a;
      bv[i] = be;
      xd[i] = xx[q] * Dc;
      aggA = a * aggA;
      aggB = a * aggB + be;
    }
  }

  // phase 2: block-exclusive scan of (aggA, aggB)
  float incA = aggA, incB = aggB;
#pragma unroll
  for (int s = 1; s < 64; s <<= 1) {
    float pA = __shfl_up(incA, (unsigned)s, 64);
    float pB = __shfl_up(incB, (unsigned)s, 64);
    if (lane >= s) {
      incB = incA * pB + incB;
      incA = incA * pA;
    }
  }
  __shared__ float wA[4], wB[4];
  if (lane == 63) {
    wA[wid] = incA;
    wB[wid] = incB;
  }
  __syncthreads();
  float wpA = 1.f, wpB = 0.f;
  for (int w = 0; w < wid; ++w) {
    float a2 = wA[w], b2 = wB[w];
    wpB = a2 * wpB + b2;
    wpA = a2 * wpA;
  }
  float eA = __shfl_up(incA, 1u, 64);
  float eB = __shfl_up(incB, 1u, 64);
  if (lane == 0) { eA = 1.f; eB = 0.f; }
  float preB = eA * wpB + eB;  // h entering this thread's segment (h_init=0)

  // phase 3: apply prefix, emit y
  float h = preB;
#pragma unroll
  for (int j = 0; j < 4; ++j) {
    float4 C4 = *(const float4*)(xb + 13 * LL + base + j * 4);
    float cvals[4] = {C4.x, C4.y, C4.z, C4.w};
    float4 o;
    float ov[4];
#pragma unroll
    for (int q = 0; q < 4; ++q) {
      int i = j * 4 + q;
      h = av[i] * h + bv[i];
      ov[q] = h * cvals[q] + xd[i];
    }
    o.x = ov[0]; o.y = ov[1]; o.z = ov[2]; o.w = ov[3];
    *(float4*)(yp + base + j * 4) = o;
  }
}

// ---------------------------------------------------------------------------
extern "C" void kernel_launch(void* const* d_in, const int* in_sizes, int n_in,
                              void* d_out, int out_size, void* d_ws,
                              size_t ws_size, hipStream_t stream) {
  const float* x        = (const float*)d_in[0];
  const float* conv_w   = (const float*)d_in[1];
  const float* conv_b   = (const float*)d_in[2];
  const float* x_proj_w = (const float*)d_in[3];
  const float* dt_w     = (const float*)d_in[4];
  const float* dt_b     = (const float*)d_in[5];
  const float* A_logs   = (const float*)d_in[6];
  const float* Ds       = (const float*)d_in[7];
  float* out = (float*)d_out;

  char* ws = (char*)d_ws;
  const size_t plane_bytes = (size_t)BB * CC * LL * sizeof(float);  // 50 MB
  float* xs   = (float*)ws;
  float* xdbl = (float*)(ws + plane_bytes);  // BB*KK*LL floats = 3.67 MB

  conv_silu_kernel<<<dim3(BB * CC), 256, 0, stream>>>(x, conv_w, conv_b, xs);
  proj_kernel<<<dim3(LL / 128, BB), 256, 0, stream>>>(xs, x_proj_w, xdbl);
  scan_kernel<<<dim3(BB * CC), 256, 0, stream>>>(xs, xdbl, dt_w, dt_b,
                                                 A_logs, Ds, out);
}

// Round 3
// 188.558 us; speedup vs baseline: 1.2868x; 1.2868x over previous
//
#include <hip/hip_runtime.h>
#include <hip/hip_bf16.h>
#include <cstddef>

// Problem constants (from reference setup_inputs)
#define BB 16
#define CC 192
#define HH 64
#define WW 64
#define LL 4096   // H*W
#define DTR 12    // dt_rank
#define KK 14     // dt_rank + 2*d_state, d_state = 1

__device__ __forceinline__ float silu_f(float v) {
  return v / (1.f + __expf(-v));
}

// ---------------------------------------------------------------------------
// K1: depthwise 5x5 conv (SAME, zero pad) + bias + SiLU
// one block per (b,c) plane; 68x72 halo tile in LDS. Each thread computes
// 4 output quads (1x4 px each) with transient 5x12 LDS window reads
// (ds_read_b128, 16B-aligned). Output stores are lane-contiguous float4.
// ---------------------------------------------------------------------------
__global__ __launch_bounds__(256) void conv_silu_kernel(
    const float* __restrict__ x, const float* __restrict__ cw,
    const float* __restrict__ cb, float* __restrict__ xs) {
  const int bc = blockIdx.x;           // b*CC + c
  const int c = bc % CC;
  const int tid = threadIdx.x;
  __shared__ float sm[68 * 72];

  const float* xp = x + (size_t)bc * LL;
  // halo: logical input (gy,gx) -> sm[(gy+2)*72 + gx+4], zero outside
  for (int i = tid; i < 68 * 72; i += 256) {
    int r = i / 72;
    int col = i - r * 72;
    int gy = r - 2, gx = col - 4;
    float v = 0.f;
    if ((unsigned)gy < 64u && (unsigned)gx < 64u) v = xp[gy * 64 + gx];
    sm[i] = v;
  }
  float w[25];
#pragma unroll
  for (int k = 0; k < 25; ++k) w[k] = cw[c * 25 + k];
  const float bias = cb[c];
  __syncthreads();

  float* op = xs + (size_t)bc * LL;
#pragma unroll
  for (int j = 0; j < 4; ++j) {
    const int quad = tid + j * 256;      // 0..1023
    const int oy = quad >> 4;            // 0..63
    const int ox = (quad & 15) * 4;      // 0..60, multiple of 4
    float acc[4] = {bias, bias, bias, bias};
#pragma unroll
    for (int ky = 0; ky < 5; ++ky) {
      // sm row oy+ky (logical gy = oy+ky-2), cols ox..ox+11 (logical gx-4)
      const float4* smr = (const float4*)&sm[(oy + ky) * 72 + ox];
      float4 r0 = smr[0], r1 = smr[1], r2 = smr[2];
      float rw[12] = {r0.x, r0.y, r0.z, r0.w, r1.x, r1.y, r1.z, r1.w,
                      r2.x, r2.y, r2.z, r2.w};
#pragma unroll
      for (int kx = 0; kx < 5; ++kx) {
        float wv = w[ky * 5 + kx];
#pragma unroll
        for (int oi = 0; oi < 4; ++oi)
          acc[oi] += rw[2 + oi + kx] * wv;   // logical gx = ox + oi + kx - 2
      }
    }
    float4 o;
    o.x = silu_f(acc[0]);
    o.y = silu_f(acc[1]);
    o.z = silu_f(acc[2]);
    o.w = silu_f(acc[3]);
    *(float4*)(op + quad * 4) = o;   // oy*64+ox == quad*4, lane-contiguous
  }
}

// ---------------------------------------------------------------------------
// K2: x_dbl[b][k][l] = sum_c x_proj_w[k][c] * xs[b][c][l]   (k = 0..13)
// block = (256-l strip, b); 4 waves x 48 channels; lane owns 4 l's (float4).
// All global loads lane-contiguous. One LDS reduce at the end.
// ---------------------------------------------------------------------------
__global__ __launch_bounds__(256) void proj_kernel(
    const float* __restrict__ xs, const float* __restrict__ xpw,
    float* __restrict__ xdbl) {
  const int b = blockIdx.y;
  const int l0 = blockIdx.x * 256;
  const int tid = threadIdx.x;
  const int lane = tid & 63;
  const int g = tid >> 6;  // wave id, 0..3

  __shared__ float part[4][KK][256];

  float4 acc[KK];
#pragma unroll
  for (int k = 0; k < KK; ++k) acc[k] = make_float4(0.f, 0.f, 0.f, 0.f);

  const float* bp = xs + ((size_t)(b * CC + g * 48)) * LL + l0 + lane * 4;
#pragma unroll 4
  for (int cc = 0; cc < 48; ++cc) {
    float4 v = *(const float4*)(bp + (size_t)cc * LL);
    const int c = g * 48 + cc;
#pragma unroll
    for (int k = 0; k < KK; ++k) {
      float wv = xpw[k * CC + c];
      acc[k].x += wv * v.x;
      acc[k].y += wv * v.y;
      acc[k].z += wv * v.z;
      acc[k].w += wv * v.w;
    }
  }
#pragma unroll
  for (int k = 0; k < KK; ++k)
    *(float4*)&part[g][k][lane * 4] = acc[k];
  __syncthreads();

  // reduce 4 wave-partials, write out (KK*256 = 3584 values, 14 iters)
  for (int idx = tid; idx < KK * 256; idx += 256) {
    int k = idx >> 8, ln = idx & 255;
    float v = part[0][k][ln] + part[1][k][ln] + part[2][k][ln] + part[3][k][ln];
    xdbl[((size_t)b * KK + k) * LL + l0 + ln] = v;
  }
}

// ---------------------------------------------------------------------------
// K3: fused dt-projection + softplus + selective scan + output.
// One WAVE (64 threads) per (b,c) sequence; 16 chunks of 256 l's; lane owns
// 4 contiguous l's per chunk (float4, lane-contiguous loads). No LDS/barriers;
// wave shfl scan + shfl(63) carry between chunks.
// ---------------------------------------------------------------------------
__global__ __launch_bounds__(64) void scan_kernel(
    const float* __restrict__ xs, const float* __restrict__ xdbl,
    const float* __restrict__ dtw, const float* __restrict__ dtb,
    const float* __restrict__ A_logs, const float* __restrict__ Ds,
    float* __restrict__ y) {
  const int bc = blockIdx.x;
  const int b = bc / CC;
  const int c = bc - b * CC;
  const int lane = threadIdx.x;

  const float Ac = -__expf(A_logs[c]);  // d_state = 1
  const float Dc = Ds[c];
  float dw[DTR];
#pragma unroll
  for (int r = 0; r < DTR; ++r) dw[r] = dtw[c * DTR + r];
  const float db = dtb[c];

  const float* xp = xs + (size_t)bc * LL;
  const float* xb = xdbl + (size_t)b * KK * LL;
  float* yp = y + (size_t)bc * LL;

  float hcarry = 0.f;

  for (int sc = 0; sc < 16; ++sc) {
    const int base = sc * 256 + lane * 4;

    float4 x4 = *(const float4*)(xp + base);
    float4 B4 = *(const float4*)(xb + 12 * LL + base);
    float4 C4 = *(const float4*)(xb + 13 * LL + base);
    float4 dr[DTR];
#pragma unroll
    for (int r = 0; r < DTR; ++r)
      dr[r] = *(const float4*)(xb + r * LL + base);

    float xx[4] = {x4.x, x4.y, x4.z, x4.w};
    float bb[4] = {B4.x, B4.y, B4.z, B4.w};
    float av[4], bv[4];
    float aggA = 1.f, aggB = 0.f;
#pragma unroll
    for (int q = 0; q < 4; ++q) {
      float z = db;
#pragma unroll
      for (int r = 0; r < DTR; ++r) z += dw[r] * ((&dr[r].x)[q]);
      float delta = (z > 15.f) ? z : __logf(1.f + __expf(z));
      float a = __expf(delta * Ac);
      float be = delta * bb[q] * xx[q];
      av[q] = a;
      bv[q] = be;
      aggA = a * aggA;
      aggB = a * aggB + be;
    }

    // wave-inclusive scan of affine (aggA, aggB), earlier lanes applied first
    float incA = aggA, incB = aggB;
#pragma unroll
    for (int s = 1; s < 64; s <<= 1) {
      float pA = __shfl_up(incA, (unsigned)s, 64);
      float pB = __shfl_up(incB, (unsigned)s, 64);
      if (lane >= s) {
        incB = incA * pB + incB;
        incA = incA * pA;
      }
    }
    // exclusive prefix for this lane
    float eA = __shfl_up(incA, 1u, 64);
    float eB = __shfl_up(incB, 1u, 64);
    if (lane == 0) { eA = 1.f; eB = 0.f; }
    // chunk aggregate (lane 63 inclusive) -> next carry
    float tA = __shfl(incA, 63, 64);
    float tB = __shfl(incB, 63, 64);

    float h = eA * hcarry + eB;
    float ov[4];
#pragma unroll
    for (int q = 0; q < 4; ++q) {
      h = av[q] * h + bv[q];
      ov[q] = h * ((&C4.x)[q]) + xx[q] * Dc;
    }
    float4 o;
    o.x = ov[0]; o.y = ov[1]; o.z = ov[2]; o.w = ov[3];
    *(float4*)(yp + base) = o;

    hcarry = tA * hcarry + tB;
  }
}

// ---------------------------------------------------------------------------
extern "C" void kernel_launch(void* const* d_in, const int* in_sizes, int n_in,
                              void* d_out, int out_size, void* d_ws,
                              size_t ws_size, hipStream_t stream) {
  const float* x        = (const float*)d_in[0];
  const float* conv_w   = (const float*)d_in[1];
  const float* conv_b   = (const float*)d_in[2];
  const float* x_proj_w = (const float*)d_in[3];
  const float* dt_w     = (const float*)d_in[4];
  const float* dt_b     = (const float*)d_in[5];
  const float* A_logs   = (const float*)d_in[6];
  const float* Ds       = (const float*)d_in[7];
  float* out = (float*)d_out;

  char* ws = (char*)d_ws;
  const size_t plane_bytes = (size_t)BB * CC * LL * sizeof(float);  // 50 MB
  float* xs   = (float*)ws;
  float* xdbl = (float*)(ws + plane_bytes);  // BB*KK*LL floats = 3.67 MB

  conv_silu_kernel<<<dim3(BB * CC), 256, 0, stream>>>(x, conv_w, conv_b, xs);
  proj_kernel<<<dim3(LL / 256, BB), 256, 0, stream>>>(xs, x_proj_w, xdbl);
  scan_kernel<<<dim3(BB * CC), 64, 0, stream>>>(xs, xdbl, dt_w, dt_b,
                                                A_logs, Ds, out);
}